// Round 1
// baseline (32.571 us; speedup 1.0000x reference)
//
#include <hip/hip_runtime.h>

// KD loss: B=2048 rows, C=16384 cols, G=8 targets per row (cols b*8+i).
// loss = (1/B) * sum_b sum_i teacher[b,i] * (lse_i(b) - t_i(b))
// lse_i = m + log(S_full - sum_{j<i} exp(t_j - m))

#define BB 2048
#define CC 16384
#define GG 8
#define NT 256
#define PER_THREAD (CC / NT)   // 64 floats per thread
#define NVEC (PER_THREAD / 4)  // 16 float4 per thread

__device__ __forceinline__ void merge_ms(float& m, float& s, float om, float os) {
    float nm = fmaxf(m, om);
    s = s * __expf(m - nm) + os * __expf(om - nm);
    m = nm;
}

__global__ __launch_bounds__(NT) void kd_row_kernel(
    const float* __restrict__ scores,
    const float* __restrict__ teacher,
    float* __restrict__ partial)
{
    const int row = blockIdx.x;
    const int tid = threadIdx.x;
    const float* rp = scores + (size_t)row * CC;
    const float4* rp4 = reinterpret_cast<const float4*>(rp);

    // single fetch of the row into registers, coalesced
    float4 v[NVEC];
#pragma unroll
    for (int i = 0; i < NVEC; ++i) {
        v[i] = rp4[i * NT + tid];
    }

    // per-thread max
    float m = -3.402823466e38f;
#pragma unroll
    for (int i = 0; i < NVEC; ++i) {
        m = fmaxf(m, fmaxf(fmaxf(v[i].x, v[i].y), fmaxf(v[i].z, v[i].w)));
    }
    // per-thread sum of exp(x - m)
    float s = 0.0f;
#pragma unroll
    for (int i = 0; i < NVEC; ++i) {
        s += expf(v[i].x - m) + expf(v[i].y - m)
           + expf(v[i].z - m) + expf(v[i].w - m);
    }

    // wave (64-lane) butterfly merge of (m, s)
#pragma unroll
    for (int off = 32; off >= 1; off >>= 1) {
        float om = __shfl_xor(m, off);
        float os = __shfl_xor(s, off);
        merge_ms(m, s, om, os);
    }

    // cross-wave merge through LDS (4 waves)
    __shared__ float sm[4], ss[4];
    const int wave = tid >> 6;
    const int lane = tid & 63;
    if (lane == 0) { sm[wave] = m; ss[wave] = s; }
    __syncthreads();

    if (tid == 0) {
        float M = sm[0], S = ss[0];
#pragma unroll
        for (int w = 1; w < 4; ++w) merge_ms(M, S, sm[w], ss[w]);

        // 8 target logits for this row: columns row*8 + i
        float t[GG];
#pragma unroll
        for (int i = 0; i < GG; ++i) t[i] = rp[row * GG + i];

        const float* tw = teacher + row * GG;
        float contrib = 0.0f;
        float S2 = S;
#pragma unroll
        for (int i = 0; i < GG; ++i) {
            float lse = M + logf(S2);
            contrib += tw[i] * (lse - t[i]);
            S2 -= expf(t[i] - M);   // mask target i for subsequent iterations
        }
        partial[row] = contrib;
    }
}

__global__ __launch_bounds__(NT) void kd_reduce_kernel(
    const float* __restrict__ partial,
    float* __restrict__ out)
{
    const int tid = threadIdx.x;
    float s = 0.0f;
    for (int i = tid; i < BB; i += NT) s += partial[i];
#pragma unroll
    for (int off = 32; off >= 1; off >>= 1) s += __shfl_xor(s, off);
    __shared__ float ws[4];
    const int wave = tid >> 6;
    const int lane = tid & 63;
    if (lane == 0) ws[wave] = s;
    __syncthreads();
    if (tid == 0) out[0] = (ws[0] + ws[1] + ws[2] + ws[3]) * (1.0f / BB);
}

extern "C" void kernel_launch(void* const* d_in, const int* in_sizes, int n_in,
                              void* d_out, int out_size, void* d_ws, size_t ws_size,
                              hipStream_t stream) {
    const float* scores  = (const float*)d_in[0];
    const float* teacher = (const float*)d_in[1];
    float* partial = (float*)d_ws;           // 2048 floats
    float* out = (float*)d_out;

    kd_row_kernel<<<BB, NT, 0, stream>>>(scores, teacher, partial);
    kd_reduce_kernel<<<1, NT, 0, stream>>>(partial, out);
}

// Round 2
// 28.955 us; speedup vs baseline: 1.1249x; 1.1249x over previous
//
#include <hip/hip_runtime.h>

// KD loss: B=2048 rows, C=16384 cols, G=8 targets per row (cols b*8+i).
// loss = (1/B) * sum_b sum_i teacher[b,i] * (lse_i(b) - t_i(b))
// lse_i = m + log(S_full - sum_{j<i} exp(t_j - m))   (masking is analytic)

#define BB 2048
#define CC 16384
#define GG 8
#define NT 512                  // 8 waves/block; 4 blocks/CU -> 32 waves/CU (full)
#define PER_THREAD (CC / NT)    // 32 floats per thread
#define NVEC (PER_THREAD / 4)   // 8 float4 per thread (~32 data VGPRs)

__device__ __forceinline__ void merge_ms(float& m, float& s, float om, float os) {
    float nm = fmaxf(m, om);
    s = s * __expf(m - nm) + os * __expf(om - nm);
    m = nm;
}

__global__ __launch_bounds__(NT, 8) void kd_row_kernel(
    const float* __restrict__ scores,
    const float* __restrict__ teacher,
    float* __restrict__ partial)
{
    const int row = blockIdx.x;
    const int tid = threadIdx.x;
    const float* rp = scores + (size_t)row * CC;
    const float4* rp4 = reinterpret_cast<const float4*>(rp);

    // Prefetch the 8 target logits + teacher weights early so their latency
    // hides under the streaming pass (they land in LDS for the epilogue).
    __shared__ float sh_t[GG], sh_w[GG];
    if (tid < GG) {
        sh_t[tid] = rp[row * GG + tid];           // target col = row*8 + i (inside this row)
        sh_w[tid] = teacher[row * GG + tid];
    }

    // single fetch of the row slice into registers, coalesced
    float4 v[NVEC];
#pragma unroll
    for (int i = 0; i < NVEC; ++i) {
        v[i] = rp4[i * NT + tid];
    }

    // per-thread max
    float m = -3.402823466e38f;
#pragma unroll
    for (int i = 0; i < NVEC; ++i) {
        m = fmaxf(m, fmaxf(fmaxf(v[i].x, v[i].y), fmaxf(v[i].z, v[i].w)));
    }
    // per-thread sum of exp(x - m)  (fast exp: v_exp_f32)
    float s = 0.0f;
#pragma unroll
    for (int i = 0; i < NVEC; ++i) {
        s += __expf(v[i].x - m) + __expf(v[i].y - m)
           + __expf(v[i].z - m) + __expf(v[i].w - m);
    }

    // wave (64-lane) butterfly merge of (m, s)
#pragma unroll
    for (int off = 32; off >= 1; off >>= 1) {
        float om = __shfl_xor(m, off);
        float os = __shfl_xor(s, off);
        merge_ms(m, s, om, os);
    }

    // cross-wave merge through LDS (8 waves)
    __shared__ float sm[NT / 64], ss[NT / 64];
    const int wave = tid >> 6;
    const int lane = tid & 63;
    if (lane == 0) { sm[wave] = m; ss[wave] = s; }
    __syncthreads();

    if (tid == 0) {
        float M = sm[0], S = ss[0];
#pragma unroll
        for (int w = 1; w < NT / 64; ++w) merge_ms(M, S, sm[w], ss[w]);

        float contrib = 0.0f;
        float S2 = S;
#pragma unroll
        for (int i = 0; i < GG; ++i) {
            float lse = M + __logf(S2);
            contrib += sh_w[i] * (lse - sh_t[i]);
            S2 -= __expf(sh_t[i] - M);   // mask target i for subsequent steps
        }
        partial[row] = contrib;
    }
}

__global__ __launch_bounds__(256) void kd_reduce_kernel(
    const float* __restrict__ partial,
    float* __restrict__ out)
{
    const int tid = threadIdx.x;
    float s = 0.0f;
    for (int i = tid; i < BB; i += 256) s += partial[i];
#pragma unroll
    for (int off = 32; off >= 1; off >>= 1) s += __shfl_xor(s, off);
    __shared__ float ws[4];
    const int wave = tid >> 6;
    const int lane = tid & 63;
    if (lane == 0) ws[wave] = s;
    __syncthreads();
    if (tid == 0) out[0] = (ws[0] + ws[1] + ws[2] + ws[3]) * (1.0f / BB);
}

extern "C" void kernel_launch(void* const* d_in, const int* in_sizes, int n_in,
                              void* d_out, int out_size, void* d_ws, size_t ws_size,
                              hipStream_t stream) {
    const float* scores  = (const float*)d_in[0];
    const float* teacher = (const float*)d_in[1];
    float* partial = (float*)d_ws;           // 2048 floats
    float* out = (float*)d_out;

    kd_row_kernel<<<BB, NT, 0, stream>>>(scores, teacher, partial);
    kd_reduce_kernel<<<1, 256, 0, stream>>>(partial, out);
}